// Round 2
// baseline (945.919 us; speedup 1.0000x reference)
//
#include <hip/hip_runtime.h>

// 2-layer GCN. Agg via dst-CSR rebuilt per call. Intermediates:
//   h1pre = x@W1            -> bf16, stored IN d_out (dead before final write)
//   hr    = relu(Agg1+b1)   -> fp32 in ws (feeds GEMM2 K-dot: keep full precision)
//   h2    = hr@W2           -> bf16 in ws (gathered by agg2)
// ws use ~78 MB.

#define N_NODES 100000

// ---------- bf16 helpers (self-contained, RN-even) ----------
__device__ __forceinline__ unsigned short f2bf(float f) {
    union { float f; unsigned u; } c; c.f = f;
    unsigned r = (c.u + 0x7fffu + ((c.u >> 16) & 1u)) >> 16;
    return (unsigned short)r;
}
__device__ __forceinline__ float bf2f(unsigned short u) {
    union { float f; unsigned u; } c; c.u = ((unsigned)u) << 16;
    return c.f;
}
__device__ __forceinline__ float2 bfpair(unsigned u) {
    union { float f; unsigned u; } a, b;
    a.u = u << 16; b.u = u & 0xffff0000u;
    return make_float2(a.f, b.f);
}

// ---------- edge dtype detection ----------
// int64 data: every 8B word < 2^32 (ids < 1e5). int32 data: packed pairs >= 2^32 w.h.p.
__global__ void detect64_k(const unsigned long long* __restrict__ ei, int* __restrict__ flag) {
    int is64 = 1;
    for (int i = 0; i < 64; ++i)
        if (ei[i] >= (1ULL << 32)) { is64 = 0; break; }
    *flag = is64;
}

__device__ __forceinline__ int edge_at(const void* ei, int is64, long long idx) {
    if (is64) return (int)((const long long*)ei)[idx];
    return ((const int*)ei)[idx];
}

__global__ void zero_k(int* __restrict__ p, int n) {
    int i = blockIdx.x * blockDim.x + threadIdx.x;
    if (i < n) p[i] = 0;
}

// ---------- degree count ----------
__global__ void count_k(const void* __restrict__ ei, const int* __restrict__ flag,
                        int* __restrict__ cnt, int E) {
    int e = blockIdx.x * blockDim.x + threadIdx.x;
    if (e >= E) return;
    int is64 = *flag;
    int d = edge_at(ei, is64, (long long)E + e);
    if ((unsigned)d < (unsigned)N_NODES) atomicAdd(&cnt[d], 1);
}

// ---------- exclusive scan, 1024 elems/block ----------
__global__ void scan1_k(const int* __restrict__ cnt, int* __restrict__ partial,
                        int* __restrict__ bsum, int n) {
    __shared__ int s[256];
    int t = threadIdx.x;
    int base = blockIdx.x * 1024 + t * 4;
    int v[4]; int loc = 0;
#pragma unroll
    for (int j = 0; j < 4; ++j) { v[j] = (base + j < n) ? cnt[base + j] : 0; loc += v[j]; }
    s[t] = loc; __syncthreads();
    for (int off = 1; off < 256; off <<= 1) {
        int x = (t >= off) ? s[t - off] : 0;
        __syncthreads();
        s[t] += x;
        __syncthreads();
    }
    int incl = s[t];
    int run = incl - loc;
    if (t == 255) bsum[blockIdx.x] = incl;
#pragma unroll
    for (int j = 0; j < 4; ++j) {
        if (base + j < n) partial[base + j] = run;
        run += v[j];
    }
}

__global__ void scan2_k(int* __restrict__ bsum, int nb) {
    __shared__ int s[256];
    int t = threadIdx.x;
    int v = (t < nb) ? bsum[t] : 0;
    s[t] = v; __syncthreads();
    for (int off = 1; off < 256; off <<= 1) {
        int x = (t >= off) ? s[t - off] : 0;
        __syncthreads();
        s[t] += x;
        __syncthreads();
    }
    if (t < nb) bsum[t] = s[t] - v;
}

__global__ void scan3_k(const int* __restrict__ bsum, const int* __restrict__ cnt,
                        int* __restrict__ row_ptr, int* __restrict__ pos,
                        float* __restrict__ dinv, int n) {
    int base = blockIdx.x * 1024 + threadIdx.x * 4;
    int add = bsum[blockIdx.x];
#pragma unroll
    for (int j = 0; j < 4; ++j) {
        int i = base + j;
        if (i < n) {
            int r = row_ptr[i] + add;
            row_ptr[i] = r;
            pos[i] = r;
            dinv[i] = rsqrtf((float)(cnt[i] + 1));  // +1 self-loop
        }
    }
}

// ---------- CSR fill ----------
__global__ void fill_k(const void* __restrict__ ei, const int* __restrict__ flag,
                       int* __restrict__ pos, int* __restrict__ colv, int E) {
    int e = blockIdx.x * blockDim.x + threadIdx.x;
    if (e >= E) return;
    int is64 = *flag;
    int s = edge_at(ei, is64, e);
    int d = edge_at(ei, is64, (long long)E + e);
    if ((unsigned)s >= (unsigned)N_NODES || (unsigned)d >= (unsigned)N_NODES) return;
    int slot = atomicAdd(&pos[d], 1);
    colv[slot] = s;
}

// ---------- fp32 GEMM: C[M,BN](bf16) = A[M,128](fp32) @ B[128,BN](fp32) ----------
template <int BN, int TN>
__global__ __launch_bounds__(256) void gemm_k(const float* __restrict__ A,
                                              const float* __restrict__ Bm,
                                              unsigned* __restrict__ C, int M) {
    constexpr int BM = 64, BK = 32, TM = 8;
    constexpr int CT = BN / TN;  // 32
    __shared__ float As[BM][BK + 1];
    __shared__ float Bs[BK][BN];
    int tid = threadIdx.x;
    int ct = tid % CT;
    int rt = tid / CT;  // 0..7
    int m0 = blockIdx.x * BM;
    float acc[TM][TN] = {};

    for (int kb = 0; kb < 128; kb += BK) {
#pragma unroll
        for (int l = 0; l < 2; ++l) {  // A: 512 float4 / 256 thr
            int f = tid + l * 256;
            int row = f >> 3;
            int kq = f & 7;
            int gr = m0 + row; if (gr >= M) gr = M - 1;
            float4 v = *(const float4*)(A + (size_t)gr * 128 + kb + kq * 4);
            As[row][kq * 4 + 0] = v.x; As[row][kq * 4 + 1] = v.y;
            As[row][kq * 4 + 2] = v.z; As[row][kq * 4 + 3] = v.w;
        }
#pragma unroll
        for (int l = 0; l < (BK * BN / 4) / 256; ++l) {  // B tile
            int f = tid + l * 256;
            int row = f / (BN / 4);
            int cq = f % (BN / 4);
            *(float4*)(&Bs[row][cq * 4]) = *(const float4*)(Bm + (size_t)(kb + row) * BN + cq * 4);
        }
        __syncthreads();
#pragma unroll
        for (int kk = 0; kk < BK; ++kk) {
            float a[TM];
#pragma unroll
            for (int i = 0; i < TM; ++i) a[i] = As[rt * TM + i][kk];
            float b[TN];
#pragma unroll
            for (int j = 0; j < TN; ++j) b[j] = Bs[kk][ct * TN + j];
#pragma unroll
            for (int i = 0; i < TM; ++i)
#pragma unroll
                for (int j = 0; j < TN; ++j) acc[i][j] = fmaf(a[i], b[j], acc[i][j]);
        }
        __syncthreads();
    }
    // store bf16-packed: BN/2 uints per row
#pragma unroll
    for (int i = 0; i < TM; ++i) {
        int gr = m0 + rt * TM + i;
        if (gr < M) {
            unsigned* crow = C + (size_t)gr * (BN / 2) + ct * (TN / 2);
#pragma unroll
            for (int j = 0; j < TN / 2; ++j) {
                unsigned lo = f2bf(acc[i][2 * j]);
                unsigned hi = f2bf(acc[i][2 * j + 1]);
                crow[j] = lo | (hi << 16);
            }
        }
    }
}

// ---------- agg1: D=128 bf16 in, fp32 out, relu ----------
__global__ __launch_bounds__(256) void agg1_k(const unsigned* __restrict__ h,  // N x 64 uints
                                              const int* __restrict__ row_ptr,
                                              const int* __restrict__ cnt,
                                              const int* __restrict__ colv,
                                              const float* __restrict__ dinv,
                                              const float* __restrict__ bias,
                                              float* __restrict__ out, int n) {
    int node = blockIdx.x * 4 + (threadIdx.x >> 6);
    if (node >= n) return;
    int lane = threadIdx.x & 63;
    float di = dinv[node];
    int start = row_ptr[node];
    int end = start + cnt[node];

    float2 hv = bfpair(h[(size_t)node * 64 + lane]);
    float w0 = di * di;
    float acc0 = w0 * hv.x, acc1 = w0 * hv.y;
    int e = start;
    for (; e + 2 <= end; e += 2) {
        int s0 = colv[e], s1 = colv[e + 1];
        float wa = di * dinv[s0], wb = di * dinv[s1];
        float2 v0 = bfpair(h[(size_t)s0 * 64 + lane]);
        float2 v1 = bfpair(h[(size_t)s1 * 64 + lane]);
        acc0 = fmaf(wa, v0.x, acc0); acc1 = fmaf(wa, v0.y, acc1);
        acc0 = fmaf(wb, v1.x, acc0); acc1 = fmaf(wb, v1.y, acc1);
    }
    if (e < end) {
        int s0 = colv[e];
        float wa = di * dinv[s0];
        float2 v0 = bfpair(h[(size_t)s0 * 64 + lane]);
        acc0 = fmaf(wa, v0.x, acc0); acc1 = fmaf(wa, v0.y, acc1);
    }
    float r0 = fmaxf(acc0 + bias[lane * 2], 0.f);
    float r1 = fmaxf(acc1 + bias[lane * 2 + 1], 0.f);
    *(float2*)(out + (size_t)node * 128 + lane * 2) = make_float2(r0, r1);
}

// ---------- agg2: D=64 bf16 in, fp32 out, no relu ----------
__global__ __launch_bounds__(256) void agg2_k(const unsigned short* __restrict__ h,  // N x 64 bf16
                                              const int* __restrict__ row_ptr,
                                              const int* __restrict__ cnt,
                                              const int* __restrict__ colv,
                                              const float* __restrict__ dinv,
                                              const float* __restrict__ bias,
                                              float* __restrict__ out, int n) {
    int node = blockIdx.x * 4 + (threadIdx.x >> 6);
    if (node >= n) return;
    int lane = threadIdx.x & 63;
    float di = dinv[node];
    int start = row_ptr[node];
    int end = start + cnt[node];

    float acc0 = di * di * bf2f(h[(size_t)node * 64 + lane]);
    int e = start;
    for (; e + 2 <= end; e += 2) {
        int s0 = colv[e], s1 = colv[e + 1];
        float wa = di * dinv[s0], wb = di * dinv[s1];
        float v0 = bf2f(h[(size_t)s0 * 64 + lane]);
        float v1 = bf2f(h[(size_t)s1 * 64 + lane]);
        acc0 = fmaf(wa, v0, acc0);
        acc0 = fmaf(wb, v1, acc0);
    }
    if (e < end) {
        int s0 = colv[e];
        acc0 = fmaf(di * dinv[s0], bf2f(h[(size_t)s0 * 64 + lane]), acc0);
    }
    out[(size_t)node * 64 + lane] = acc0 + bias[lane];
}

// ---------- launch ----------
extern "C" void kernel_launch(void* const* d_in, const int* in_sizes, int n_in,
                              void* d_out, int out_size, void* d_ws, size_t ws_size,
                              hipStream_t stream) {
    const float* x  = (const float*)d_in[0];
    const void*  ei = d_in[1];
    const float* W1 = (const float*)d_in[2];
    const float* b1 = (const float*)d_in[3];
    const float* W2 = (const float*)d_in[4];
    const float* b2 = (const float*)d_in[5];

    const int N = N_NODES;
    const int E = in_sizes[1] / 2;

    char* w = (char*)d_ws;
    size_t off = 0;
    auto take = [&](size_t bytes) {
        void* p = w + off;
        off = (off + bytes + 255) & ~(size_t)255;
        return p;
    };
    int*   flag    = (int*)take(sizeof(int));
    int*   cnt     = (int*)take((size_t)N * 4);
    int*   row_ptr = (int*)take((size_t)N * 4);
    int*   pos     = (int*)take((size_t)N * 4);
    int*   bsum    = (int*)take(128 * 4);
    float* dinv    = (float*)take((size_t)N * 4);
    int*   colv    = (int*)take((size_t)E * 4);
    float* hr      = (float*)take((size_t)N * 128 * 4);       // fp32, 51.2 MB
    unsigned short* h2 = (unsigned short*)take((size_t)N * 64 * 2);  // bf16, 12.8 MB
    (void)ws_size; (void)n_in; (void)out_size;

    // h1pre (bf16, N x 128) lives in d_out — dead before agg2's final write.
    unsigned* h1pre = (unsigned*)d_out;

    const int nscan = (N + 1023) / 1024;  // 98

    detect64_k<<<1, 1, 0, stream>>>((const unsigned long long*)ei, flag);
    zero_k<<<(N + 255) / 256, 256, 0, stream>>>(cnt, N);
    count_k<<<(E + 255) / 256, 256, 0, stream>>>(ei, flag, cnt, E);
    scan1_k<<<nscan, 256, 0, stream>>>(cnt, row_ptr, bsum, N);
    scan2_k<<<1, 256, 0, stream>>>(bsum, nscan);
    scan3_k<<<nscan, 256, 0, stream>>>(bsum, cnt, row_ptr, pos, dinv, N);
    fill_k<<<(E + 255) / 256, 256, 0, stream>>>(ei, flag, pos, colv, E);

    // layer 1: x@W1 -> h1pre(bf16, in d_out); Agg+relu -> hr(fp32)
    gemm_k<128, 4><<<(N + 63) / 64, 256, 0, stream>>>(x, W1, h1pre, N);
    agg1_k<<<(N + 3) / 4, 256, 0, stream>>>(h1pre, row_ptr, cnt, colv, dinv, b1, hr, N);
    // layer 2: hr@W2 -> h2(bf16); Agg -> d_out(fp32)
    gemm_k<64, 2><<<(N + 63) / 64, 256, 0, stream>>>(hr, W2, (unsigned*)h2, N);
    agg2_k<<<(N + 3) / 4, 256, 0, stream>>>(h2, row_ptr, cnt, colv, dinv, b2, (float*)d_out, N);
}

// Round 3
// 844.906 us; speedup vs baseline: 1.1196x; 1.1196x over previous
//
#include <hip/hip_runtime.h>

// 2-layer GCN. dst-CSR rebuilt per call with STRIPED scatter (L2-resident stripe
// regions kill the 15x partial-line writeback amplification seen in R2).
// Intermediates:
//   e32_src/e32_dst: edge_index converted to int32 once per call
//   h1pre = x@W1          -> bf16, stored IN d_out (dead before final write)
//   hr    = relu(Agg1+b1) -> bf16 in ws
//   h2    = hr@W2         -> bf16 in ws
// ws use ~79 MB.

#define N_NODES 100000
#define STRIPE_SHIFT 14
#define NSTRIPES ((N_NODES + (1 << STRIPE_SHIFT) - 1) >> STRIPE_SHIFT)  // 7

// ---------- bf16 helpers (RN-even) ----------
__device__ __forceinline__ unsigned short f2bf(float f) {
    union { float f; unsigned u; } c; c.f = f;
    unsigned r = (c.u + 0x7fffu + ((c.u >> 16) & 1u)) >> 16;
    return (unsigned short)r;
}
__device__ __forceinline__ float bf2f(unsigned short u) {
    union { float f; unsigned u; } c; c.u = ((unsigned)u) << 16;
    return c.f;
}
__device__ __forceinline__ float2 bfpair(unsigned u) {
    union { float f; unsigned u; } a, b;
    a.u = u << 16; b.u = u & 0xffff0000u;
    return make_float2(a.f, b.f);
}
__device__ __forceinline__ unsigned packbf(float a, float b) {
    return (unsigned)f2bf(a) | ((unsigned)f2bf(b) << 16);
}

// ---------- edge dtype detection ----------
__global__ void detect64_k(const unsigned long long* __restrict__ ei, int* __restrict__ flag) {
    int is64 = 1;
    for (int i = 0; i < 64; ++i)
        if (ei[i] >= (1ULL << 32)) { is64 = 0; break; }
    *flag = is64;
}

__device__ __forceinline__ int edge_at(const void* ei, int is64, long long idx) {
    if (is64) return (int)((const long long*)ei)[idx];
    return ((const int*)ei)[idx];
}

// ---------- convert edge_index -> int32 src/dst ----------
__global__ void convert_k(const void* __restrict__ ei, const int* __restrict__ flag,
                          int* __restrict__ esrc, int* __restrict__ edst, int E) {
    int e = blockIdx.x * blockDim.x + threadIdx.x;
    if (e >= E) return;
    int is64 = *flag;
    esrc[e] = edge_at(ei, is64, e);
    edst[e] = edge_at(ei, is64, (long long)E + e);
}

__global__ void zero_k(int* __restrict__ p, int n) {
    int i = blockIdx.x * blockDim.x + threadIdx.x;
    if (i < n) p[i] = 0;
}

// ---------- degree count ----------
__global__ void count_k(const int* __restrict__ edst, int* __restrict__ cnt, int E) {
    int e = blockIdx.x * blockDim.x + threadIdx.x;
    if (e >= E) return;
    int d = edst[e];
    if ((unsigned)d < (unsigned)N_NODES) atomicAdd(&cnt[d], 1);
}

// ---------- exclusive scan, 1024 elems/block ----------
__global__ void scan1_k(const int* __restrict__ cnt, int* __restrict__ partial,
                        int* __restrict__ bsum, int n) {
    __shared__ int s[256];
    int t = threadIdx.x;
    int base = blockIdx.x * 1024 + t * 4;
    int v[4]; int loc = 0;
#pragma unroll
    for (int j = 0; j < 4; ++j) { v[j] = (base + j < n) ? cnt[base + j] : 0; loc += v[j]; }
    s[t] = loc; __syncthreads();
    for (int off = 1; off < 256; off <<= 1) {
        int x = (t >= off) ? s[t - off] : 0;
        __syncthreads();
        s[t] += x;
        __syncthreads();
    }
    int incl = s[t];
    int run = incl - loc;
    if (t == 255) bsum[blockIdx.x] = incl;
#pragma unroll
    for (int j = 0; j < 4; ++j) {
        if (base + j < n) partial[base + j] = run;
        run += v[j];
    }
}

__global__ void scan2_k(int* __restrict__ bsum, int nb) {
    __shared__ int s[256];
    int t = threadIdx.x;
    int v = (t < nb) ? bsum[t] : 0;
    s[t] = v; __syncthreads();
    for (int off = 1; off < 256; off <<= 1) {
        int x = (t >= off) ? s[t - off] : 0;
        __syncthreads();
        s[t] += x;
        __syncthreads();
    }
    if (t < nb) bsum[t] = s[t] - v;
}

__global__ void scan3_k(const int* __restrict__ bsum, const int* __restrict__ cnt,
                        int* __restrict__ row_ptr, int* __restrict__ pos,
                        float* __restrict__ dinv, int n) {
    int base = blockIdx.x * 1024 + threadIdx.x * 4;
    int add = bsum[blockIdx.x];
#pragma unroll
    for (int j = 0; j < 4; ++j) {
        int i = base + j;
        if (i < n) {
            int r = row_ptr[i] + add;
            row_ptr[i] = r;
            pos[i] = r;
            dinv[i] = rsqrtf((float)(cnt[i] + 1));  // +1 self-loop
        }
    }
}

// ---------- striped CSR fill: stripes processed sequentially for L2 locality ----------
__global__ __launch_bounds__(256) void fill_stripe_k(const int* __restrict__ esrc,
                                                     const int* __restrict__ edst,
                                                     int* __restrict__ pos,
                                                     int* __restrict__ colv, int E) {
    int stride = gridDim.x * blockDim.x;
    int tid = blockIdx.x * blockDim.x + threadIdx.x;
    for (int s = 0; s < NSTRIPES; ++s) {
        for (int e = tid; e < E; e += stride) {
            int d = edst[e];
            if ((d >> STRIPE_SHIFT) != s) continue;
            if ((unsigned)d >= (unsigned)N_NODES) continue;
            int sv = esrc[e];
            int slot = atomicAdd(&pos[d], 1);
            colv[slot] = sv;
        }
    }
}

// ---------- GEMM1: C[M,128](bf16 packed) = A[M,128](fp32) @ B[128,128](fp32) ----------
__global__ __launch_bounds__(256) void gemm1_k(const float* __restrict__ A,
                                               const float* __restrict__ Bm,
                                               unsigned* __restrict__ C, int M) {
    constexpr int BM = 64, BK = 32, TM = 8, BN = 128, TN = 4, CT = BN / TN;  // 32
    __shared__ float As[BM][BK + 1];
    __shared__ float Bs[BK][BN];
    int tid = threadIdx.x;
    int ct = tid % CT;
    int rt = tid / CT;  // 0..7
    int m0 = blockIdx.x * BM;
    float acc[TM][TN] = {};

    for (int kb = 0; kb < 128; kb += BK) {
#pragma unroll
        for (int l = 0; l < 2; ++l) {  // A: 512 float4 / 256 thr
            int f = tid + l * 256;
            int row = f >> 3;
            int kq = f & 7;
            int gr = m0 + row; if (gr >= M) gr = M - 1;
            float4 v = *(const float4*)(A + (size_t)gr * 128 + kb + kq * 4);
            As[row][kq * 4 + 0] = v.x; As[row][kq * 4 + 1] = v.y;
            As[row][kq * 4 + 2] = v.z; As[row][kq * 4 + 3] = v.w;
        }
#pragma unroll
        for (int l = 0; l < 4; ++l) {  // B: 32x128 floats = 1024 float4
            int f = tid + l * 256;
            int row = f >> 5;
            int cq = f & 31;
            *(float4*)(&Bs[row][cq * 4]) = *(const float4*)(Bm + (size_t)(kb + row) * BN + cq * 4);
        }
        __syncthreads();
#pragma unroll
        for (int kk = 0; kk < BK; ++kk) {
            float a[TM];
#pragma unroll
            for (int i = 0; i < TM; ++i) a[i] = As[rt * TM + i][kk];
            float b[TN];
#pragma unroll
            for (int j = 0; j < TN; ++j) b[j] = Bs[kk][ct * TN + j];
#pragma unroll
            for (int i = 0; i < TM; ++i)
#pragma unroll
                for (int j = 0; j < TN; ++j) acc[i][j] = fmaf(a[i], b[j], acc[i][j]);
        }
        __syncthreads();
    }
#pragma unroll
    for (int i = 0; i < TM; ++i) {
        int gr = m0 + rt * TM + i;
        if (gr < M) {
            unsigned* crow = C + (size_t)gr * 64 + ct * 2;
            crow[0] = packbf(acc[i][0], acc[i][1]);
            crow[1] = packbf(acc[i][2], acc[i][3]);
        }
    }
}

// ---------- GEMM2: C[M,64](bf16) = A[M,128](bf16 packed) @ B[128,64](fp32) ----------
__global__ __launch_bounds__(256) void gemm2_k(const unsigned* __restrict__ A,  // M x 64 uints
                                               const float* __restrict__ Bm,   // 128 x 64
                                               unsigned* __restrict__ C,       // M x 32 uints
                                               int M) {
    constexpr int BM = 64, BK = 32, TM = 8, BN = 64, TN = 2, CT = BN / TN;  // 32
    __shared__ float As[BM][BK + 1];
    __shared__ float Bs[BK][BN];
    int tid = threadIdx.x;
    int ct = tid % CT;
    int rt = tid / CT;
    int m0 = blockIdx.x * BM;
    float acc[TM][TN] = {};

    for (int kb = 0; kb < 128; kb += BK) {
        {  // A: 64 rows x 4 uint4 = 256 loads
            int row = tid >> 2, kq = tid & 3;
            int gr = m0 + row; if (gr >= M) gr = M - 1;
            uint4 v = *((const uint4*)(A + (size_t)gr * 64 + kb / 2) + kq);
            float2 p0 = bfpair(v.x), p1 = bfpair(v.y), p2 = bfpair(v.z), p3 = bfpair(v.w);
            float* dst = &As[row][kq * 8];
            dst[0] = p0.x; dst[1] = p0.y; dst[2] = p1.x; dst[3] = p1.y;
            dst[4] = p2.x; dst[5] = p2.y; dst[6] = p3.x; dst[7] = p3.y;
        }
#pragma unroll
        for (int l = 0; l < 2; ++l) {  // B: 32x64 = 512 float4
            int f = tid + l * 256;
            int row = f >> 4;
            int cq = f & 15;
            *(float4*)(&Bs[row][cq * 4]) = *(const float4*)(Bm + (size_t)(kb + row) * BN + cq * 4);
        }
        __syncthreads();
#pragma unroll
        for (int kk = 0; kk < BK; ++kk) {
            float a[TM];
#pragma unroll
            for (int i = 0; i < TM; ++i) a[i] = As[rt * TM + i][kk];
            float b0 = Bs[kk][ct * 2], b1 = Bs[kk][ct * 2 + 1];
#pragma unroll
            for (int i = 0; i < TM; ++i) {
                acc[i][0] = fmaf(a[i], b0, acc[i][0]);
                acc[i][1] = fmaf(a[i], b1, acc[i][1]);
            }
        }
        __syncthreads();
    }
#pragma unroll
    for (int i = 0; i < TM; ++i) {
        int gr = m0 + rt * TM + i;
        if (gr < M) C[(size_t)gr * 32 + ct] = packbf(acc[i][0], acc[i][1]);
    }
}

// ---------- agg1: D=128 bf16 in, bf16 out, relu ----------
__global__ __launch_bounds__(256) void agg1_k(const unsigned* __restrict__ h,  // N x 64 uints
                                              const int* __restrict__ row_ptr,
                                              const int* __restrict__ cnt,
                                              const int* __restrict__ colv,
                                              const float* __restrict__ dinv,
                                              const float* __restrict__ bias,
                                              unsigned* __restrict__ out, int n) {
    int node = blockIdx.x * 4 + (threadIdx.x >> 6);
    if (node >= n) return;
    int lane = threadIdx.x & 63;
    float di = dinv[node];
    int start = row_ptr[node];
    int end = start + cnt[node];

    float2 hv = bfpair(h[(size_t)node * 64 + lane]);
    float w0 = di * di;
    float acc0 = w0 * hv.x, acc1 = w0 * hv.y;
    int e = start;
    for (; e + 2 <= end; e += 2) {
        int s0 = colv[e], s1 = colv[e + 1];
        float wa = di * dinv[s0], wb = di * dinv[s1];
        float2 v0 = bfpair(h[(size_t)s0 * 64 + lane]);
        float2 v1 = bfpair(h[(size_t)s1 * 64 + lane]);
        acc0 = fmaf(wa, v0.x, acc0); acc1 = fmaf(wa, v0.y, acc1);
        acc0 = fmaf(wb, v1.x, acc0); acc1 = fmaf(wb, v1.y, acc1);
    }
    if (e < end) {
        int s0 = colv[e];
        float wa = di * dinv[s0];
        float2 v0 = bfpair(h[(size_t)s0 * 64 + lane]);
        acc0 = fmaf(wa, v0.x, acc0); acc1 = fmaf(wa, v0.y, acc1);
    }
    float r0 = fmaxf(acc0 + bias[lane * 2], 0.f);
    float r1 = fmaxf(acc1 + bias[lane * 2 + 1], 0.f);
    out[(size_t)node * 64 + lane] = packbf(r0, r1);
}

// ---------- agg2: D=64 bf16 in, fp32 out ----------
__global__ __launch_bounds__(256) void agg2_k(const unsigned short* __restrict__ h,  // N x 64 bf16
                                              const int* __restrict__ row_ptr,
                                              const int* __restrict__ cnt,
                                              const int* __restrict__ colv,
                                              const float* __restrict__ dinv,
                                              const float* __restrict__ bias,
                                              float* __restrict__ out, int n) {
    int node = blockIdx.x * 4 + (threadIdx.x >> 6);
    if (node >= n) return;
    int lane = threadIdx.x & 63;
    float di = dinv[node];
    int start = row_ptr[node];
    int end = start + cnt[node];

    float acc0 = di * di * bf2f(h[(size_t)node * 64 + lane]);
    int e = start;
    for (; e + 2 <= end; e += 2) {
        int s0 = colv[e], s1 = colv[e + 1];
        float wa = di * dinv[s0], wb = di * dinv[s1];
        float v0 = bf2f(h[(size_t)s0 * 64 + lane]);
        float v1 = bf2f(h[(size_t)s1 * 64 + lane]);
        acc0 = fmaf(wa, v0, acc0);
        acc0 = fmaf(wb, v1, acc0);
    }
    if (e < end) {
        int s0 = colv[e];
        acc0 = fmaf(di * dinv[s0], bf2f(h[(size_t)s0 * 64 + lane]), acc0);
    }
    out[(size_t)node * 64 + lane] = acc0 + bias[lane];
}

// ---------- launch ----------
extern "C" void kernel_launch(void* const* d_in, const int* in_sizes, int n_in,
                              void* d_out, int out_size, void* d_ws, size_t ws_size,
                              hipStream_t stream) {
    const float* x  = (const float*)d_in[0];
    const void*  ei = d_in[1];
    const float* W1 = (const float*)d_in[2];
    const float* b1 = (const float*)d_in[3];
    const float* W2 = (const float*)d_in[4];
    const float* b2 = (const float*)d_in[5];

    const int N = N_NODES;
    const int E = in_sizes[1] / 2;

    char* w = (char*)d_ws;
    size_t off = 0;
    auto take = [&](size_t bytes) {
        void* p = w + off;
        off = (off + bytes + 255) & ~(size_t)255;
        return p;
    };
    int*   flag    = (int*)take(sizeof(int));
    int*   cnt     = (int*)take((size_t)N * 4);
    int*   row_ptr = (int*)take((size_t)N * 4);
    int*   pos     = (int*)take((size_t)N * 4);
    int*   bsum    = (int*)take(128 * 4);
    float* dinv    = (float*)take((size_t)N * 4);
    int*   esrc    = (int*)take((size_t)E * 4);
    int*   edst    = (int*)take((size_t)E * 4);
    int*   colv    = (int*)take((size_t)E * 4);
    unsigned* hr   = (unsigned*)take((size_t)N * 64 * 4);       // bf16 N x 128
    unsigned short* h2 = (unsigned short*)take((size_t)N * 64 * 2);
    (void)ws_size; (void)n_in; (void)out_size;

    // h1pre (bf16, N x 128) lives in d_out — dead before agg2's final write.
    unsigned* h1pre = (unsigned*)d_out;

    const int nscan = (N + 1023) / 1024;  // 98

    detect64_k<<<1, 1, 0, stream>>>((const unsigned long long*)ei, flag);
    convert_k<<<(E + 255) / 256, 256, 0, stream>>>(ei, flag, esrc, edst, E);
    zero_k<<<(N + 255) / 256, 256, 0, stream>>>(cnt, N);
    count_k<<<(E + 255) / 256, 256, 0, stream>>>(edst, cnt, E);
    scan1_k<<<nscan, 256, 0, stream>>>(cnt, row_ptr, bsum, N);
    scan2_k<<<1, 256, 0, stream>>>(bsum, nscan);
    scan3_k<<<nscan, 256, 0, stream>>>(bsum, cnt, row_ptr, pos, dinv, N);
    fill_stripe_k<<<1024, 256, 0, stream>>>(esrc, edst, pos, colv, E);

    // layer 1
    gemm1_k<<<(N + 63) / 64, 256, 0, stream>>>(x, W1, h1pre, N);
    agg1_k<<<(N + 3) / 4, 256, 0, stream>>>(h1pre, row_ptr, cnt, colv, dinv, b1, hr, N);
    // layer 2
    gemm2_k<<<(N + 63) / 64, 256, 0, stream>>>(hr, W2, (unsigned*)h2, N);
    agg2_k<<<(N + 3) / 4, 256, 0, stream>>>(h2, row_ptr, cnt, colv, dinv, b2, (float*)d_out, N);
}